// Round 4
// baseline (395.553 us; speedup 1.0000x reference)
//
#include <hip/hip_runtime.h>

#define T_STEPS 4096
#define BLOCK   256                 // 4 waves = 4 independent rows per block
#define CHUNK   16                  // elements per lane per tile
#define TILE    (64 * CHUNK)        // 1024
#define NTILES  (T_STEPS / TILE)    // 4
#define RPB     (BLOCK / 64)        // rows per block

constexpr float CAP     = 13.5f;
constexpr float MAXR    = 5.0f;
constexpr float S0      = 6.75f;
constexpr float DT      = (float)(5.0 / 60.0);
constexpr float FIVE_DT = 5.0f * DT;
constexpr float INV_DT  = 1.0f / DT;      // reciprocal-mul replaces IEEE divide
constexpr float INV_1K  = 1.0f / 1000.0f; // clip is 1-Lipschitz: safe through chain

typedef float vfloat4 __attribute__((ext_vector_type(4)));  // native vec for nt stores

struct Trip { float d, l, h; };     // s -> clip(s + d, l, h)

// apply p first, then q
__device__ __forceinline__ Trip combine(const Trip& p, const Trip& q) {
    Trip r;
    r.d = p.d + q.d;
    r.l = fminf(fmaxf(p.l + q.d, q.l), q.h);
    r.h = fminf(fmaxf(p.h + q.d, q.l), q.h);
    return r;
}

__device__ __forceinline__ void nt_store4(float* p, float a, float b, float c, float d) {
    vfloat4 v = {a, b, c, d};
    __builtin_nontemporal_store(v, reinterpret_cast<vfloat4*>(p));
}

__global__ __launch_bounds__(BLOCK, 2) void battery_kernel(
    const float* __restrict__ ga, const float* __restrict__ pa,
    const float* __restrict__ pp, const float* __restrict__ pr,
    float* __restrict__ trace, float* __restrict__ cost, int B)
{
    const int tid  = threadIdx.x;
    const int lane = tid & 63;
    const int wv   = tid >> 6;
    const int row  = blockIdx.x * RPB + wv;

    // per-WAVE private staging buffer; element E lives at E + (E>>4):
    //   writes go to 17*lane+j  -> stride 17 (odd) = exactly 2 lanes/bank = free
    //   reads  at lane+(lane>>4)+68m -> 2-3 lanes/bank = ~free
    __shared__ float buf[RPB][TILE + TILE / 16];
    float* sb = buf[wv];

    if (row >= B) return;

    const long long rowOff = (long long)row * T_STEPS;
    const long long trBase = (long long)row * (T_STEPS + 1);
    const float* gaR = ga + rowOff;
    const float* paR = pa + rowOff;
    const float* ppR = pp + rowOff;
    const float* prR = pr + rowOff;

    if (lane == 0) trace[trBase] = S0;

    // prefetch tile 0: 4 streams x 4 float4 per lane (64B/lane/stream)
    const int b0 = lane * CHUNK;
    float4 cg0 = *reinterpret_cast<const float4*>(gaR + b0);
    float4 cg1 = *reinterpret_cast<const float4*>(gaR + b0 + 4);
    float4 cg2 = *reinterpret_cast<const float4*>(gaR + b0 + 8);
    float4 cg3 = *reinterpret_cast<const float4*>(gaR + b0 + 12);
    float4 cp0 = *reinterpret_cast<const float4*>(paR + b0);
    float4 cp1 = *reinterpret_cast<const float4*>(paR + b0 + 4);
    float4 cp2 = *reinterpret_cast<const float4*>(paR + b0 + 8);
    float4 cp3 = *reinterpret_cast<const float4*>(paR + b0 + 12);
    float4 cq0 = *reinterpret_cast<const float4*>(ppR + b0);
    float4 cq1 = *reinterpret_cast<const float4*>(ppR + b0 + 4);
    float4 cq2 = *reinterpret_cast<const float4*>(ppR + b0 + 8);
    float4 cq3 = *reinterpret_cast<const float4*>(ppR + b0 + 12);
    float4 cr0 = *reinterpret_cast<const float4*>(prR + b0);
    float4 cr1 = *reinterpret_cast<const float4*>(prR + b0 + 4);
    float4 cr2 = *reinterpret_cast<const float4*>(prR + b0 + 8);
    float4 cr3 = *reinterpret_cast<const float4*>(prR + b0 + 12);

    float s = S0;   // exact row state entering the current tile

    for (int k = 0; k < NTILES; ++k) {
        // issue next tile's loads first (16 KB/wave in flight), fence so the
        // scheduler cannot sink them into their use
        const int kn = (k + 1 < NTILES) ? k + 1 : k;
        const int nb = kn * TILE + lane * CHUNK;
        float4 ng0 = *reinterpret_cast<const float4*>(gaR + nb);
        float4 ng1 = *reinterpret_cast<const float4*>(gaR + nb + 4);
        float4 ng2 = *reinterpret_cast<const float4*>(gaR + nb + 8);
        float4 ng3 = *reinterpret_cast<const float4*>(gaR + nb + 12);
        float4 np0 = *reinterpret_cast<const float4*>(paR + nb);
        float4 np1 = *reinterpret_cast<const float4*>(paR + nb + 4);
        float4 np2 = *reinterpret_cast<const float4*>(paR + nb + 8);
        float4 np3 = *reinterpret_cast<const float4*>(paR + nb + 12);
        float4 nq0 = *reinterpret_cast<const float4*>(ppR + nb);
        float4 nq1 = *reinterpret_cast<const float4*>(ppR + nb + 4);
        float4 nq2 = *reinterpret_cast<const float4*>(ppR + nb + 8);
        float4 nq3 = *reinterpret_cast<const float4*>(ppR + nb + 12);
        float4 nr0 = *reinterpret_cast<const float4*>(prR + nb);
        float4 nr1 = *reinterpret_cast<const float4*>(prR + nb + 4);
        float4 nr2 = *reinterpret_cast<const float4*>(prR + nb + 8);
        float4 nr3 = *reinterpret_cast<const float4*>(prR + nb + 12);
        __builtin_amdgcn_sched_barrier(0);

        const float gaA[16] = {cg0.x,cg0.y,cg0.z,cg0.w, cg1.x,cg1.y,cg1.z,cg1.w,
                               cg2.x,cg2.y,cg2.z,cg2.w, cg3.x,cg3.y,cg3.z,cg3.w};
        const float paA[16] = {cp0.x,cp0.y,cp0.z,cp0.w, cp1.x,cp1.y,cp1.z,cp1.w,
                               cp2.x,cp2.y,cp2.z,cp2.w, cp3.x,cp3.y,cp3.z,cp3.w};
        const float ppA[16] = {cq0.x,cq0.y,cq0.z,cq0.w, cq1.x,cq1.y,cq1.z,cq1.w,
                               cq2.x,cq2.y,cq2.z,cq2.w, cq3.x,cq3.y,cq3.z,cq3.w};
        const float prA[16] = {cr0.x,cr0.y,cr0.z,cr0.w, cr1.x,cr1.y,cr1.z,cr1.w,
                               cr2.x,cr2.y,cr2.z,cr2.w, cr3.x,cr3.y,cr3.z,cr3.w};

        // ---- phase 1: compose this lane's 16 contiguous steps ----
        float aA[16], agrA[16];
        Trip acc;
        #pragma unroll
        for (int j = 0; j < CHUNK; ++j) {
            float rate = fminf(fmaxf(paA[j] * ppA[j], 0.0f), MAXR);
            float a    = rate * DT;                   // prov_pv_amount
            float agr  = gaA[j] * MAXR;
            float u    = agr * DT;
            aA[j] = a; agrA[j] = agr;
            Trip f;
            f.d = a + fminf(fmaxf(u, -FIVE_DT), FIVE_DT - a);
            f.l = 0.0f;
            f.h = fminf(fmaxf(CAP + u, CAP - FIVE_DT), CAP);
            acc = (j == 0) ? f : combine(acc, f);
        }

        // ---- wave-level inclusive scan (64 lanes = 1024 steps) ----
        #pragma unroll
        for (int off = 1; off < 64; off <<= 1) {
            Trip p;
            p.d = __shfl_up(acc.d, off);
            p.l = __shfl_up(acc.l, off);
            p.h = __shfl_up(acc.h, off);
            if (lane >= off) acc = combine(p, acc);
        }

        // exclusive -> state entering this lane's chunk
        float exd = __shfl_up(acc.d, 1);
        float exl = __shfl_up(acc.l, 1);
        float exh = __shfl_up(acc.h, 1);
        float scur = fminf(fmaxf(s + exd, exl), exh);
        if (lane == 0) scur = s;

        // ---- phase 2: faithful replay, divide-free; state -> LDS inline ----
        float ct[16];
        #pragma unroll
        for (int j = 0; j < CHUNK; ++j) {
            float after_pv  = fminf(fmaxf(scur + aA[j], 0.0f), CAP);
            float realised  = after_pv - scur;
            float apr       = realised * INV_DT;
            float pv_export = realised - ppA[j] * DT;
            float rgr       = fminf(fmaxf(agrA[j], -MAXR), MAXR - apr);
            float ns        = fminf(fmaxf(after_pv + rgr * DT, 0.0f), CAP);
            float grid_amt  = ns - after_pv;
            sb[17 * lane + j] = ns;                   // E=16*lane+j -> E+(E>>4)
            ct[j] = (prA[j] * INV_1K) * (grid_amt + pv_export);
            scur  = ns;
        }
        s = __shfl(scur, 63);   // EXACT state chaining into next tile

        // cost [B,T]: aligned nontemporal float4 stores (never re-read ->
        // keep the 128 MB of output out of L3 so inputs stay resident)
        const long long cb = rowOff + (long long)k * TILE + lane * CHUNK;
        nt_store4(cost + cb,      ct[0],  ct[1],  ct[2],  ct[3]);
        nt_store4(cost + cb + 4,  ct[4],  ct[5],  ct[6],  ct[7]);
        nt_store4(cost + cb + 8,  ct[8],  ct[9],  ct[10], ct[11]);
        nt_store4(cost + cb + 12, ct[12], ct[13], ct[14], ct[15]);

        // trace [B,T+1]: +1 breaks alignment -> per-wave LDS transpose, then
        // coalesced nontemporal scalar stores (same-wave DS ops in-order)
        __builtin_amdgcn_wave_barrier();
        const long long tb = trBase + 1 + (long long)k * TILE;
        #pragma unroll
        for (int m = 0; m < CHUNK; ++m) {
            int E = lane + 64 * m;
            __builtin_nontemporal_store(sb[E + (E >> 4)], trace + tb + E);
        }
        __builtin_amdgcn_wave_barrier();

        // rotate prefetch double-buffer
        cg0=ng0; cg1=ng1; cg2=ng2; cg3=ng3;
        cp0=np0; cp1=np1; cp2=np2; cp3=np3;
        cq0=nq0; cq1=nq1; cq2=nq2; cq3=nq3;
        cr0=nr0; cr1=nr1; cr2=nr2; cr3=nr3;
    }
}

extern "C" void kernel_launch(void* const* d_in, const int* in_sizes, int n_in,
                              void* d_out, int out_size, void* d_ws, size_t ws_size,
                              hipStream_t stream) {
    const float* ga = (const float*)d_in[0];   // grid_action
    const float* pa = (const float*)d_in[1];   // pv_action
    const float* pp = (const float*)d_in[2];   // pv_power
    const float* pr = (const float*)d_in[3];   // price
    const int B = in_sizes[0] / T_STEPS;
    float* trace = (float*)d_out;
    float* cost  = (float*)d_out + (long long)B * (T_STEPS + 1);
    const int grid = (B + RPB - 1) / RPB;
    battery_kernel<<<grid, BLOCK, 0, stream>>>(ga, pa, pp, pr, trace, cost, B);
}

// Round 5
// 322.466 us; speedup vs baseline: 1.2266x; 1.2266x over previous
//
#include <hip/hip_runtime.h>

#define T_STEPS 4096
#define BLOCK   256                 // 4 waves = 4 independent rows per block
#define CHUNK   16                  // elements per lane per tile
#define TILE    (64 * CHUNK)        // 1024
#define NTILES  (T_STEPS / TILE)    // 4
#define RPB     (BLOCK / 64)        // rows per block

constexpr float CAP     = 13.5f;
constexpr float MAXR    = 5.0f;
constexpr float S0      = 6.75f;
constexpr float DT      = (float)(5.0 / 60.0);
constexpr float FIVE_DT = 5.0f * DT;
constexpr float INV_DT  = 1.0f / DT;      // reciprocal-mul replaces IEEE divide
constexpr float INV_1K  = 1.0f / 1000.0f; // clip is 1-Lipschitz: safe through chain

struct Trip { float d, l, h; };     // s -> clip(s + d, l, h)

// apply p first, then q
__device__ __forceinline__ Trip combine(const Trip& p, const Trip& q) {
    Trip r;
    r.d = p.d + q.d;
    r.l = fminf(fmaxf(p.l + q.d, q.l), q.h);
    r.h = fminf(fmaxf(p.h + q.d, q.l), q.h);
    return r;
}

__global__ __launch_bounds__(BLOCK, 2) void battery_kernel(
    const float* __restrict__ ga, const float* __restrict__ pa,
    const float* __restrict__ pp, const float* __restrict__ pr,
    float* __restrict__ trace, float* __restrict__ cost, int B)
{
    const int tid  = threadIdx.x;
    const int lane = tid & 63;
    const int wv   = tid >> 6;
    const int row  = blockIdx.x * RPB + wv;

    // per-WAVE private staging buffer; element E lives at E + (E>>4):
    //   writes go to 17*lane+j  -> stride 17 (odd) = exactly 2 lanes/bank = free
    //   reads  at lane+(lane>>4)+68m -> 2-3 lanes/bank = ~free
    __shared__ float buf[RPB][TILE + TILE / 16];
    float* sb = buf[wv];

    if (row >= B) return;

    const long long rowOff = (long long)row * T_STEPS;
    const long long trBase = (long long)row * (T_STEPS + 1);
    const float* gaR = ga + rowOff;
    const float* paR = pa + rowOff;
    const float* ppR = pp + rowOff;
    const float* prR = pr + rowOff;

    if (lane == 0) trace[trBase] = S0;

    // prefetch tile 0: 4 streams x 4 float4 per lane (64B/lane/stream)
    const int b0 = lane * CHUNK;
    float4 cg0 = *reinterpret_cast<const float4*>(gaR + b0);
    float4 cg1 = *reinterpret_cast<const float4*>(gaR + b0 + 4);
    float4 cg2 = *reinterpret_cast<const float4*>(gaR + b0 + 8);
    float4 cg3 = *reinterpret_cast<const float4*>(gaR + b0 + 12);
    float4 cp0 = *reinterpret_cast<const float4*>(paR + b0);
    float4 cp1 = *reinterpret_cast<const float4*>(paR + b0 + 4);
    float4 cp2 = *reinterpret_cast<const float4*>(paR + b0 + 8);
    float4 cp3 = *reinterpret_cast<const float4*>(paR + b0 + 12);
    float4 cq0 = *reinterpret_cast<const float4*>(ppR + b0);
    float4 cq1 = *reinterpret_cast<const float4*>(ppR + b0 + 4);
    float4 cq2 = *reinterpret_cast<const float4*>(ppR + b0 + 8);
    float4 cq3 = *reinterpret_cast<const float4*>(ppR + b0 + 12);
    float4 cr0 = *reinterpret_cast<const float4*>(prR + b0);
    float4 cr1 = *reinterpret_cast<const float4*>(prR + b0 + 4);
    float4 cr2 = *reinterpret_cast<const float4*>(prR + b0 + 8);
    float4 cr3 = *reinterpret_cast<const float4*>(prR + b0 + 12);

    float s = S0;   // exact row state entering the current tile

    for (int k = 0; k < NTILES; ++k) {
        // issue next tile's loads first (16 KB/wave in flight), fence so the
        // scheduler cannot sink them into their use
        const int kn = (k + 1 < NTILES) ? k + 1 : k;
        const int nb = kn * TILE + lane * CHUNK;
        float4 ng0 = *reinterpret_cast<const float4*>(gaR + nb);
        float4 ng1 = *reinterpret_cast<const float4*>(gaR + nb + 4);
        float4 ng2 = *reinterpret_cast<const float4*>(gaR + nb + 8);
        float4 ng3 = *reinterpret_cast<const float4*>(gaR + nb + 12);
        float4 np0 = *reinterpret_cast<const float4*>(paR + nb);
        float4 np1 = *reinterpret_cast<const float4*>(paR + nb + 4);
        float4 np2 = *reinterpret_cast<const float4*>(paR + nb + 8);
        float4 np3 = *reinterpret_cast<const float4*>(paR + nb + 12);
        float4 nq0 = *reinterpret_cast<const float4*>(ppR + nb);
        float4 nq1 = *reinterpret_cast<const float4*>(ppR + nb + 4);
        float4 nq2 = *reinterpret_cast<const float4*>(ppR + nb + 8);
        float4 nq3 = *reinterpret_cast<const float4*>(ppR + nb + 12);
        float4 nr0 = *reinterpret_cast<const float4*>(prR + nb);
        float4 nr1 = *reinterpret_cast<const float4*>(prR + nb + 4);
        float4 nr2 = *reinterpret_cast<const float4*>(prR + nb + 8);
        float4 nr3 = *reinterpret_cast<const float4*>(prR + nb + 12);
        __builtin_amdgcn_sched_barrier(0);

        const float gaA[16] = {cg0.x,cg0.y,cg0.z,cg0.w, cg1.x,cg1.y,cg1.z,cg1.w,
                               cg2.x,cg2.y,cg2.z,cg2.w, cg3.x,cg3.y,cg3.z,cg3.w};
        const float paA[16] = {cp0.x,cp0.y,cp0.z,cp0.w, cp1.x,cp1.y,cp1.z,cp1.w,
                               cp2.x,cp2.y,cp2.z,cp2.w, cp3.x,cp3.y,cp3.z,cp3.w};
        const float ppA[16] = {cq0.x,cq0.y,cq0.z,cq0.w, cq1.x,cq1.y,cq1.z,cq1.w,
                               cq2.x,cq2.y,cq2.z,cq2.w, cq3.x,cq3.y,cq3.z,cq3.w};
        const float prA[16] = {cr0.x,cr0.y,cr0.z,cr0.w, cr1.x,cr1.y,cr1.z,cr1.w,
                               cr2.x,cr2.y,cr2.z,cr2.w, cr3.x,cr3.y,cr3.z,cr3.w};

        // ---- phase 1: compose this lane's 16 contiguous steps ----
        float aA[16], agrA[16];
        Trip acc;
        #pragma unroll
        for (int j = 0; j < CHUNK; ++j) {
            float rate = fminf(fmaxf(paA[j] * ppA[j], 0.0f), MAXR);
            float a    = rate * DT;                   // prov_pv_amount
            float agr  = gaA[j] * MAXR;
            float u    = agr * DT;
            aA[j] = a; agrA[j] = agr;
            Trip f;
            f.d = a + fminf(fmaxf(u, -FIVE_DT), FIVE_DT - a);
            f.l = 0.0f;
            f.h = fminf(fmaxf(CAP + u, CAP - FIVE_DT), CAP);
            acc = (j == 0) ? f : combine(acc, f);
        }

        // ---- wave-level inclusive scan (64 lanes = 1024 steps) ----
        #pragma unroll
        for (int off = 1; off < 64; off <<= 1) {
            Trip p;
            p.d = __shfl_up(acc.d, off);
            p.l = __shfl_up(acc.l, off);
            p.h = __shfl_up(acc.h, off);
            if (lane >= off) acc = combine(p, acc);
        }

        // exclusive -> state entering this lane's chunk
        float exd = __shfl_up(acc.d, 1);
        float exl = __shfl_up(acc.l, 1);
        float exh = __shfl_up(acc.h, 1);
        float scur = fminf(fmaxf(s + exd, exl), exh);
        if (lane == 0) scur = s;

        // ---- phase 2: faithful replay, divide-free; state -> LDS inline ----
        float ct[16];
        #pragma unroll
        for (int j = 0; j < CHUNK; ++j) {
            float after_pv  = fminf(fmaxf(scur + aA[j], 0.0f), CAP);
            float realised  = after_pv - scur;
            float apr       = realised * INV_DT;
            float pv_export = realised - ppA[j] * DT;
            float rgr       = fminf(fmaxf(agrA[j], -MAXR), MAXR - apr);
            float ns        = fminf(fmaxf(after_pv + rgr * DT, 0.0f), CAP);
            float grid_amt  = ns - after_pv;
            sb[17 * lane + j] = ns;                   // E=16*lane+j -> E+(E>>4)
            ct[j] = (prA[j] * INV_1K) * (grid_amt + pv_export);
            scur  = ns;
        }
        s = __shfl(scur, 63);   // EXACT state chaining into next tile

        // cost [B,T]: plain cached float4 stores — L2 merges to full lines
        // (nt stores REGRESSED: no-allocate sub-line writes amplified
        //  WRITE_SIZE 134->227 MB; never use nt below 64B granularity)
        const long long cb = rowOff + (long long)k * TILE + lane * CHUNK;
        *reinterpret_cast<float4*>(cost + cb)      = make_float4(ct[0],  ct[1],  ct[2],  ct[3]);
        *reinterpret_cast<float4*>(cost + cb + 4)  = make_float4(ct[4],  ct[5],  ct[6],  ct[7]);
        *reinterpret_cast<float4*>(cost + cb + 8)  = make_float4(ct[8],  ct[9],  ct[10], ct[11]);
        *reinterpret_cast<float4*>(cost + cb + 12) = make_float4(ct[12], ct[13], ct[14], ct[15]);

        // trace [B,T+1]: +1 breaks alignment -> per-wave LDS transpose, then
        // coalesced cached scalar stores (same-wave DS ops in-order)
        __builtin_amdgcn_wave_barrier();
        const long long tb = trBase + 1 + (long long)k * TILE;
        #pragma unroll
        for (int m = 0; m < CHUNK; ++m) {
            int E = lane + 64 * m;
            trace[tb + E] = sb[E + (E >> 4)];
        }
        __builtin_amdgcn_wave_barrier();

        // rotate prefetch double-buffer
        cg0=ng0; cg1=ng1; cg2=ng2; cg3=ng3;
        cp0=np0; cp1=np1; cp2=np2; cp3=np3;
        cq0=nq0; cq1=nq1; cq2=nq2; cq3=nq3;
        cr0=nr0; cr1=nr1; cr2=nr2; cr3=nr3;
    }
}

extern "C" void kernel_launch(void* const* d_in, const int* in_sizes, int n_in,
                              void* d_out, int out_size, void* d_ws, size_t ws_size,
                              hipStream_t stream) {
    const float* ga = (const float*)d_in[0];   // grid_action
    const float* pa = (const float*)d_in[1];   // pv_action
    const float* pp = (const float*)d_in[2];   // pv_power
    const float* pr = (const float*)d_in[3];   // price
    const int B = in_sizes[0] / T_STEPS;
    float* trace = (float*)d_out;
    float* cost  = (float*)d_out + (long long)B * (T_STEPS + 1);
    const int grid = (B + RPB - 1) / RPB;
    battery_kernel<<<grid, BLOCK, 0, stream>>>(ga, pa, pp, pr, trace, cost, B);
}